// Round 1
// baseline (262.053 us; speedup 1.0000x reference)
//
#include <hip/hip_runtime.h>

// Capsule routing, fully fused: one block per batch b, 3 routing iterations
// with zero u_hat materialization.
//   B=256, S=512, D_in=256, NC=16, DC=32, ROUTINGS=3
// Per block (1024 thr = 16 waves):
//   phase0: v0 = (1/16)*colsum(U)            (one 512KB pass over U[b])
//   out1   = squash(v0 @ W_n)                (tiny W-GEMM, fp32)
//   iter k: w~[n] = W_n @ out_k  ->  pass over U: Y=U·w~^T (MFMA),
//           softmax over n, V += C^T·U (MFMA) -> out_{k+1} = squash(V @ W_n)

#define SDIM 512
#define DIN  256
#define NCAP 16
#define DCAP 32
#define OC   512

typedef __attribute__((ext_vector_type(8))) __bf16 bf16x8;
typedef __attribute__((ext_vector_type(4))) float f32x4;
typedef __attribute__((ext_vector_type(4))) unsigned short u16x4;

static_assert(sizeof(bf16x8) == 16, "bf16x8 must be 16B");

__device__ __forceinline__ unsigned short f2bf(float f) {
  unsigned u = __float_as_uint(f);
  u += 0x7FFFu + ((u >> 16) & 1u);   // RNE to bf16
  return (unsigned short)(u >> 16);
}

__global__ __launch_bounds__(1024) void caps_fused(
    const float* __restrict__ Uall, const float* __restrict__ Wg,
    float* __restrict__ outp)
{
  // 61440 B total static LDS (< 64KB)
  __shared__ __align__(16) unsigned short sU16[64 * 256];   // 32KB bf16 chunk, XOR-swz by ((row&7)<<3)
  __shared__ __align__(16) unsigned short sWt16[16 * 256];  // 8KB  w~ bf16, XOR-swz by ((n&7)<<3)
  __shared__ __align__(16) unsigned short sCT16[16 * 64];   // 2KB  C^T bf16 (row n, col s), swz; aliases sSS
  __shared__ __align__(16) float sV[16 * 256];              // 16KB V accum / colsum partials
  __shared__ __align__(16) float sOut[512];                 // 2KB  out (n*32+d), fp32

  float* sSS = (float*)sCT16;  // 256 floats (1KB) — lifetime disjoint from sCT use

  const int tid = threadIdx.x;
  const int w = tid >> 6;      // wave 0..15
  const int l = tid & 63;      // lane
  const int b = blockIdx.x;
  const float* U = Uall + (size_t)b * (SDIM * DIN);
  const float4* g4 = (const float4*)U;

  // ---------------- phase 0: v0 = (1/16) * sum_s U[s][:] ----------------
  {
    float4 a = make_float4(0.f, 0.f, 0.f, 0.f);
    const int base = (w * 32) * 64 + l;   // float4 index: row (w*32), col 4l
    #pragma unroll 8
    for (int r = 0; r < 32; ++r) {
      float4 v = g4[base + r * 64];
      a.x += v.x; a.y += v.y; a.z += v.z; a.w += v.w;
    }
    *(float4*)&sV[w * 256 + 4 * l] = a;   // 16 partials per column
  }
  __syncthreads();
  if (tid < 256) {
    float s = 0.f;
    #pragma unroll
    for (int q = 0; q < 16; ++q) s += sV[q * 256 + tid];
    sSS[tid] = s * (1.0f / 16.0f);
  }
  __syncthreads();

  // ---------------- helpers ----------------
  // out = squash over d of (x @ W_n); x[n][i] = mode ? sV[n][i] : sSS[i]
  auto outCompute = [&](int mode) {
    if (tid < 512) {
      const int c = tid;            // n*32+d
      const int n = c >> 5;
      float p0 = 0.f, p1 = 0.f, p2 = 0.f, p3 = 0.f;
      #pragma unroll 4
      for (int i = 0; i < 256; i += 4) {
        float x0 = mode ? sV[n * 256 + i + 0] : sSS[i + 0];
        float x1 = mode ? sV[n * 256 + i + 1] : sSS[i + 1];
        float x2 = mode ? sV[n * 256 + i + 2] : sSS[i + 2];
        float x3 = mode ? sV[n * 256 + i + 3] : sSS[i + 3];
        p0 = fmaf(Wg[(i + 0) * OC + c], x0, p0);
        p1 = fmaf(Wg[(i + 1) * OC + c], x1, p1);
        p2 = fmaf(Wg[(i + 2) * OC + c], x2, p2);
        p3 = fmaf(Wg[(i + 3) * OC + c], x3, p3);
      }
      float p = (p0 + p1) + (p2 + p3);
      float sq = p * p;
      #pragma unroll
      for (int off = 1; off < 32; off <<= 1) sq += __shfl_xor(sq, off);
      sOut[c] = p * rsqrtf(sq + 1e-7f);
    }
    __syncthreads();
  };

  // sWt[n][i] = sum_d W[i][n*32+d] * out[n*32+d]
  auto wtCompute = [&]() {
    const int f4 = tid & 127;      // float4-col within W row
    const int rr = tid >> 7;       // 0..7 (row-in-group)
    const float4 ov = *(const float4*)&sOut[4 * f4];
    #pragma unroll 4
    for (int it = 0; it < 32; ++it) {
      const int i = it * 8 + rr;
      const float4 wv = *(const float4*)&Wg[i * OC + 4 * f4];
      float p = wv.x * ov.x + wv.y * ov.y + wv.z * ov.z + wv.w * ov.w;
      p += __shfl_xor(p, 1);
      p += __shfl_xor(p, 2);
      p += __shfl_xor(p, 4);
      if ((f4 & 7) == 0) {
        const int n = f4 >> 3;
        sWt16[(n * 256 + i) ^ ((n & 7) << 3)] = f2bf(p);
      }
    }
    __syncthreads();
  };

  auto stage = [&](const float4* pre) {
    #pragma unroll
    for (int k = 0; k < 4; ++k) {
      const int s = w + 16 * k;          // row in chunk
      u16x4 h;
      h[0] = f2bf(pre[k].x); h[1] = f2bf(pre[k].y);
      h[2] = f2bf(pre[k].z); h[3] = f2bf(pre[k].w);
      *(u16x4*)&sU16[(s * 256 + 4 * l) ^ ((s & 7) << 3)] = h;
    }
  };

  // one routing pass: Y = U·w~^T (per 64-row chunk), softmax over n, V += C^T·U
  auto pass = [&]() {
    f32x4 vacc = {0.f, 0.f, 0.f, 0.f};
    const int nr = l & 15;
    const int grp = l >> 4;
    {
      float4 pre[4];
      #pragma unroll
      for (int k = 0; k < 4; ++k) pre[k] = g4[(w + 16 * k) * 64 + l];
      stage(pre);
    }
    __syncthreads();
    for (int chunk = 0; chunk < 8; ++chunk) {
      float4 nxt[4];
      if (chunk < 7) {
        #pragma unroll
        for (int k = 0; k < 4; ++k)
          nxt[k] = g4[((chunk + 1) * 64 + w + 16 * k) * 64 + l];
      }
      // ---- GEMM1 (waves 0..3): Y[64x16] = chunk[64x256] · w~^T ----
      if (w < 4) {
        f32x4 y = {0.f, 0.f, 0.f, 0.f};
        const int arow = 16 * w + nr;
        #pragma unroll
        for (int ks = 0; ks < 8; ++ks) {
          bf16x8 a = *(const bf16x8*)&sU16[(arow * 256 + ks * 32 + grp * 8) ^ ((arow & 7) << 3)];
          bf16x8 bw = *(const bf16x8*)&sWt16[(nr * 256 + ks * 32 + grp * 8) ^ ((nr & 7) << 3)];
          y = __builtin_amdgcn_mfma_f32_16x16x32_bf16(a, bw, y, 0, 0, 0);
        }
        // y[r] = Y[s = 16w + grp*4 + r][n = nr] ; softmax over n (16-lane groups)
        float y0 = y[0], y1 = y[1], y2 = y[2], y3 = y[3];
        float m0 = y0, m1 = y1, m2 = y2, m3 = y3;
        #pragma unroll
        for (int off = 1; off < 16; off <<= 1) {
          m0 = fmaxf(m0, __shfl_xor(m0, off));
          m1 = fmaxf(m1, __shfl_xor(m1, off));
          m2 = fmaxf(m2, __shfl_xor(m2, off));
          m3 = fmaxf(m3, __shfl_xor(m3, off));
        }
        float e0 = __expf(y0 - m0), e1 = __expf(y1 - m1);
        float e2 = __expf(y2 - m2), e3 = __expf(y3 - m3);
        float s0 = e0, s1 = e1, s2 = e2, s3 = e3;
        #pragma unroll
        for (int off = 1; off < 16; off <<= 1) {
          s0 += __shfl_xor(s0, off);
          s1 += __shfl_xor(s1, off);
          s2 += __shfl_xor(s2, off);
          s3 += __shfl_xor(s3, off);
        }
        u16x4 cw;
        cw[0] = f2bf(e0 / s0); cw[1] = f2bf(e1 / s1);
        cw[2] = f2bf(e2 / s2); cw[3] = f2bf(e3 / s3);
        // C^T: row n=nr, cols s = 16w + 4*grp + (0..3)
        *(u16x4*)&sCT16[(nr * 64 + 16 * w + 4 * grp) ^ ((nr & 7) << 3)] = cw;
      }
      __syncthreads();
      // ---- GEMM2 (all 16 waves): V[16 x 256] += C^T[16x64] · chunk[64x256] ----
      {
        const int icol = 16 * w + nr;     // i column this lane contributes
        #pragma unroll
        for (int ks = 0; ks < 2; ++ks) {
          bf16x8 a = *(const bf16x8*)&sCT16[(nr * 64 + ks * 32 + grp * 8) ^ ((nr & 7) << 3)];
          bf16x8 bb;
          const int s0b = ks * 32 + grp * 8;
          #pragma unroll
          for (int j = 0; j < 8; ++j) {
            unsigned short v = sU16[((s0b + j) * 256 + icol) ^ (j << 3)];
            bb[j] = __builtin_bit_cast(__bf16, v);
          }
          vacc = __builtin_amdgcn_mfma_f32_16x16x32_bf16(a, bb, vacc, 0, 0, 0);
        }
      }
      __syncthreads();
      if (chunk < 7) stage(nxt);
      __syncthreads();
    }
    // vacc[r] = V[n = grp*4 + r][i = 16w + nr]
    #pragma unroll
    for (int r = 0; r < 4; ++r) sV[(grp * 4 + r) * 256 + 16 * w + nr] = vacc[r];
    __syncthreads();
  };

  // ---------------- routing ----------------
  outCompute(0);        // out1 from v0
  wtCompute();          // w~ from out1
  pass();               // -> V (iter 2 weights)
  outCompute(1);        // out2
  wtCompute();          // w~ from out2
  pass();               // -> V (iter 3 weights)
  outCompute(1);        // out3

  if (tid < 512) outp[(size_t)b * 512 + tid] = sOut[tid];
}

extern "C" void kernel_launch(void* const* d_in, const int* in_sizes, int n_in,
                              void* d_out, int out_size, void* d_ws, size_t ws_size,
                              hipStream_t stream) {
  const float* u = (const float*)d_in[0];
  const float* Wg = (const float*)d_in[1];
  float* out = (float*)d_out;
  dim3 grid(256), block(1024);
  hipLaunchKernelGGL(caps_fused, grid, block, 0, stream, u, Wg, out);
}